// Round 4
// baseline (45695.853 us; speedup 1.0000x reference)
//
#include <hip/hip_runtime.h>
#include <math.h>

#define T_STEPS 8192
#define I_DIM   64
#define H_DIM   2048
#define O_DIM   128
#define NBLK    256     // one block per CU; each CU owns 8 h-indices
#define NTHR    512     // 8 waves; wave w owns h-index cu*8+w (all 4 gate rows)
#define NSLOT   4       // h slot ring depth (reset 2 ahead)
#define NAN_BITS 0x7FC00000u

typedef unsigned int v4u __attribute__((ext_vector_type(4)));
typedef float        v4f __attribute__((ext_vector_type(4)));

__device__ __forceinline__ float sigmoid_f(float x) {
    return 1.0f / (1.0f + __expf(-x));
}
__device__ __forceinline__ float tanh_fast(float x) {
    // 2*sigmoid(2x)-1; saturates correctly for |x| large (exp -> 0 / inf)
    return 2.0f / (1.0f + __expf(-2.0f * x)) - 1.0f;
}

__global__ void init_ws_kernel(unsigned int* Hbits) {
    int tid = blockIdx.x * blockDim.x + threadIdx.x;
    if (tid < NSLOT * H_DIM) {
        // slot 0 = h_0 = 0.0f; slots 1..3 = NaN sentinel ("not ready")
        Hbits[tid] = (tid < H_DIM) ? 0u : NAN_BITS;
    }
}

// Persistent LSTM. One block/CU, 8 waves. Wave w owns h-index hidx=cu*8+w and
// its 4 gate rows g*2048+hidx. Data-as-flag (NaN sentinel) h ring in LLC; no
// fences. Single barrier per step via double-buffered LDS h.
// k-mapping: lane l covers k = 256*m + 4*l + j (m=0..7, j=0..3) -> ds_read_b128.
__global__ __launch_bounds__(NTHR, 2) void lstm_persistent(
    const float* __restrict__ x,     // [T, 64]
    const float* __restrict__ Wih,   // [8192, 64]
    const float* __restrict__ Whh,   // [8192, 2048]
    const float* __restrict__ bih,   // [8192]
    const float* __restrict__ bhh,   // [8192]
    unsigned int* __restrict__ Hbits)// [NSLOT][2048] in ws (float bits)
{
    const int cu   = blockIdx.x;
    const int tid  = threadIdx.x;
    const int w    = tid >> 6;
    const int lane = tid & 63;
    const int hidx = cu * 8 + w;     // owned h index

    __shared__ float hbuf[2][H_DIM];   // 16 KB double buffer

    // ---- one-time: W_hh rows for the 4 gates of hidx into registers ----
    float wreg[4][8][4];
#pragma unroll
    for (int g = 0; g < 4; g++) {
        const float* rp = Whh + (size_t)(g * H_DIM + hidx) * H_DIM;
#pragma unroll
        for (int m = 0; m < 8; m++) {
            v4f wv = *(const v4f*)(rp + m * 256 + lane * 4);  // coalesced 16B
            wreg[g][m][0] = wv[0]; wreg[g][m][1] = wv[1];
            wreg[g][m][2] = wv[2]; wreg[g][m][3] = wv[3];
        }
    }
    // W_ih: lane l holds column l of the 4 gate rows
    float xwih[4];
#pragma unroll
    for (int g = 0; g < 4; g++)
        xwih[g] = Wih[(size_t)(g * H_DIM + hidx) * I_DIM + lane];
    // biases (used by lane 0 only)
    float bias[4];
#pragma unroll
    for (int g = 0; g < 4; g++)
        bias[g] = bih[g * H_DIM + hidx] + bhh[g * H_DIM + hidx];

    float cstate = 0.0f;   // live in lane 0 of each wave

    for (int t = 0; t < T_STEPS; t++) {
        const int sr = t & (NSLOT - 1);
        const int sw = (t + 1) & (NSLOT - 1);
        const int sz = (t + 2) & (NSLOT - 1);
        const int pb = t & 1;

        float xv = x[(size_t)t * I_DIM + lane];   // issue before the spin

        // ---- 1. spin on own 16B of h_t (data-as-flag), stage to LDS ----
        {
            const unsigned int* Hr = Hbits + sr * H_DIM + tid * 4;
            v4u u;
            do {
                asm volatile(
                    "global_load_dwordx4 %0, %1, off sc0 sc1\n\t"
                    "s_waitcnt vmcnt(0)"
                    : "=v"(u) : "v"(Hr) : "memory");
            } while (u[0] == NAN_BITS || u[1] == NAN_BITS ||
                     u[2] == NAN_BITS || u[3] == NAN_BITS);
            *(v4u*)&hbuf[pb][tid * 4] = u;
        }
        // reset own dword 2 slots ahead (holds fully-consumed h_{t-2}); same
        // thread republishes this exact address at step t+1 -> same-addr order.
        if (lane == 0) {
            __hip_atomic_store(Hbits + sz * H_DIM + hidx, NAN_BITS,
                               __ATOMIC_RELAXED, __HIP_MEMORY_SCOPE_AGENT);
        }
        __syncthreads();   // the ONLY barrier per step

        // ---- 2. dot products: 4 gate rows, 8 x (b128 LDS + 16 FMA) ----
        float a0 = 0.f, a1 = 0.f, a2 = 0.f, a3 = 0.f;
#pragma unroll
        for (int m = 0; m < 8; m++) {
            v4f hv = *(const v4f*)&hbuf[pb][m * 256 + lane * 4];
            a0 += wreg[0][m][0] * hv[0] + wreg[0][m][1] * hv[1]
                + wreg[0][m][2] * hv[2] + wreg[0][m][3] * hv[3];
            a1 += wreg[1][m][0] * hv[0] + wreg[1][m][1] * hv[1]
                + wreg[1][m][2] * hv[2] + wreg[1][m][3] * hv[3];
            a2 += wreg[2][m][0] * hv[0] + wreg[2][m][1] * hv[1]
                + wreg[2][m][2] * hv[2] + wreg[2][m][3] * hv[3];
            a3 += wreg[3][m][0] * hv[0] + wreg[3][m][1] * hv[1]
                + wreg[3][m][2] * hv[2] + wreg[3][m][3] * hv[3];
        }
        // fold in W_ih * x_t (lane l holds column l)
        a0 += xwih[0] * xv;
        a1 += xwih[1] * xv;
        a2 += xwih[2] * xv;
        a3 += xwih[3] * xv;

        // ---- 3. butterfly reduce to lane 0 ----
#pragma unroll
        for (int off = 32; off; off >>= 1) {
            a0 += __shfl_xor(a0, off, 64);
            a1 += __shfl_xor(a1, off, 64);
            a2 += __shfl_xor(a2, off, 64);
            a3 += __shfl_xor(a3, off, 64);
        }

        // ---- 4. elementwise + publish (lane 0 of this wave; no 2nd barrier) ----
        if (lane == 0) {
            float iv = sigmoid_f(a0 + bias[0]);
            float fv = sigmoid_f(a1 + bias[1]);
            float gv = tanh_fast(a2 + bias[2]);
            float ov = sigmoid_f(a3 + bias[3]);
            cstate = fv * cstate + iv * gv;
            float hval = ov * tanh_fast(cstate);
            __hip_atomic_store(Hbits + sw * H_DIM + hidx, __float_as_uint(hval),
                               __ATOMIC_RELAXED, __HIP_MEMORY_SCOPE_AGENT);
        }
        // next-step staging targets the other LDS buffer; barrier A of step t+1
        // protects buffer reuse at t+2.
    }
}

// Final linear: out[o] = h_T . W_lin[o,:] + b_lin[o].  One wave per output.
// h_T lives in slot (T & 3) == 0.
__global__ void final_linear(const float* __restrict__ hT,
                             const float* __restrict__ Wlin,
                             const float* __restrict__ blin,
                             float* __restrict__ out)
{
    int gw   = (blockIdx.x * blockDim.x + threadIdx.x) >> 6;
    int lane = threadIdx.x & 63;
    if (gw < O_DIM) {
        const float* wp = Wlin + (size_t)gw * H_DIM;
        float s = 0.f;
        for (int k = lane; k < H_DIM; k += 64)
            s += wp[k] * hT[k];
#pragma unroll
        for (int off = 32; off; off >>= 1) s += __shfl_xor(s, off, 64);
        if (lane == 0) out[gw] = s + blin[gw];
    }
}

extern "C" void kernel_launch(void* const* d_in, const int* in_sizes, int n_in,
                              void* d_out, int out_size, void* d_ws, size_t ws_size,
                              hipStream_t stream)
{
    const float* x    = (const float*)d_in[0];
    const float* Wih  = (const float*)d_in[1];
    const float* Whh  = (const float*)d_in[2];
    const float* bih  = (const float*)d_in[3];
    const float* bhh  = (const float*)d_in[4];
    const float* Wlin = (const float*)d_in[5];
    const float* blin = (const float*)d_in[6];
    float* out = (float*)d_out;

    unsigned int* Hbits = (unsigned int*)d_ws;

    hipLaunchKernelGGL(init_ws_kernel, dim3((NSLOT * H_DIM + 255) / 256), dim3(256),
                       0, stream, Hbits);

    void* args[] = { (void*)&x, (void*)&Wih, (void*)&Whh, (void*)&bih, (void*)&bhh,
                     (void*)&Hbits };
    hipLaunchCooperativeKernel(reinterpret_cast<void*>(lstm_persistent),
                               dim3(NBLK), dim3(NTHR), args, 0, stream);

    // h_T is in slot (T_STEPS & 3) == 0
    hipLaunchKernelGGL(final_linear, dim3(32), dim3(256), 0, stream,
                       (const float*)Hbits, Wlin, blin, out);
}